// Round 4
// baseline (95.966 us; speedup 1.0000x reference)
//
#include <hip/hip_runtime.h>

typedef unsigned long long u64;

#define S_LEN 2048
#define BATCH 8
#define NTOK 64
#define DMODEL 648
#define NBLK 32   // 32 blocks of 64 positions

// Workspace layout (u64 units):
//   P  [BATCH][2048]     @ 0      : bit jj of P[b][w*64+t]        = (src[64w+jj]   == t)
//   SH [BATCH][4][2048]  @ 16384  : bit jj of SH[b][d-1][w*64+t]  = (src[64w+jj-d] == t)
//   sT [BATCH][S_LEN]    @ 81920  : transposed src column (int)

// ---------------------------------------------------------------------------
// Build: one 64-thread wave per (block w, batch b). Lane j holds token at
// position 64w+j; per-token masks via __ballot; lane t keeps token-t masks.
// Four pre-shifted tables (shift d=1..4, cross-block carry from prev block).
// ---------------------------------------------------------------------------
__global__ __launch_bounds__(64) void build_kernel(const int* __restrict__ src,
                                                   u64* __restrict__ P,
                                                   u64* __restrict__ SH,
                                                   int* __restrict__ sT) {
    const int w = blockIdx.x, b = blockIdx.y;
    const int lane = threadIdx.x;
    const int p = (w << 6) + lane;
    const int tok  = src[p * BATCH + b];
    const int tokp = (w > 0) ? src[(p - 64) * BATCH + b] : -1;  // prev block
    u64 m_sel = 0, mp_sel = 0;
    #pragma unroll 8
    for (int t = 0; t < NTOK; ++t) {
        const u64 m  = __ballot(tok == t);
        const u64 mp = __ballot(tokp == t);
        if (lane == t) { m_sel = m; mp_sel = mp; }
    }
    const int idx = (w << 6) + lane;        // lane == token slot
    P[b * 2048 + idx] = m_sel;
    u64* S = SH + (size_t)b * 8192;
    S[0 * 2048 + idx] = (m_sel << 1) | (mp_sel >> 63);
    S[1 * 2048 + idx] = (m_sel << 2) | (mp_sel >> 62);
    S[2 * 2048 + idx] = (m_sel << 3) | (mp_sel >> 61);
    S[3 * 2048 + idx] = (m_sel << 4) | (mp_sel >> 60);
    sT[b * S_LEN + p] = tok;
}

// ---------------------------------------------------------------------------
// Compute: WG = 256 threads = 4 waves; each wave owns 8 consecutive q of one
// batch column. Lane = token id. Fully branchless inner loop:
//   A1 = S1[w][s[q]] & pv          (pv = P[w][lane], per-lane coalesced)
//   A2 = A1 & S2[w][s[q-1]]
//   A3 = A2 & S3[w][s[q-2]]
//   A4 = A3 & S4[w][s[q-3]]
//   h_i[lane] += popc(A_i);  c_i = wave-sum of h_i (epilogue shfl reduce).
// All table reads are wave-uniform-address LDS broadcasts -> no conflicts,
// no branches -> compiler batches the 32 ds_reads per block iteration.
// ---------------------------------------------------------------------------
__global__ __launch_bounds__(256, 2) void compute_kernel(const u64* __restrict__ P,
                                                         const u64* __restrict__ SH,
                                                         const int* __restrict__ sT,
                                                         float* __restrict__ out) {
    __shared__ u64 L[4 * 2048];   // 64 KiB: the 4 shifted tables for this b

    const int b = blockIdx.y;
    const int tid = threadIdx.x;
    const int lane = tid & 63;
    const int wv = tid >> 6;

    {   // stage tables (contiguous 64 KiB, 16B vector copies)
        const ulonglong2* G = (const ulonglong2*)(SH + (size_t)b * 8192);
        ulonglong2* Ld = (ulonglong2*)L;
        #pragma unroll 4
        for (int i = tid; i < 4096; i += 256) Ld[i] = G[i];
    }
    __syncthreads();

    const int o = blockIdx.x * 4 + wv;                    // 0..255
    const int qoct = (o & 1) ? (255 - (o >> 1)) : (o >> 1); // load balance
    const int q0 = qoct << 3;

    const int* s = sT + b * S_LEN;
    const u64* Pb = P + (size_t)b * 2048;

    int tk[12];
    #pragma unroll
    for (int i = 0; i < 12; ++i) {
        const int idx = q0 - 4 + i;
        tk[i] = (idx >= 0) ? s[idx] : 0;   // clamp: provably-dead lookups only
    }

    int hh[8][4] = {};
    int cuP[8];
    int cuF = 0;
    const int wq = q0 >> 6, rem0 = q0 & 63;

    u64 pv = Pb[lane];  // block 0 per-lane token mask
    for (int w = 0; w < wq; ++w) {
        const u64 pvn = Pb[((w + 1) << 6) + lane];  // prefetch next block
        cuF += __popcll(pv);
        const int wb = w << 6;
        #pragma unroll
        for (int r = 0; r < 8; ++r) {
            const u64 A1 = L[wb + tk[4 + r]] & pv;
            const u64 A2 = A1 & L[2048 + wb + tk[3 + r]];
            const u64 A3 = A2 & L[4096 + wb + tk[2 + r]];
            const u64 A4 = A3 & L[6144 + wb + tk[1 + r]];
            hh[r][0] += __popcll(A1);
            hh[r][1] += __popcll(A2);
            hh[r][2] += __popcll(A3);
            hh[r][3] += __popcll(A4);
        }
        pv = pvn;
    }

    {   // partial block w = wq: j-bits jj < rem0 + r
        const int wb = wq << 6;
        #pragma unroll
        for (int r = 0; r < 8; ++r) {
            const int rem = rem0 + r;                  // <= 63 always
            const u64 valid = (1ull << rem) - 1ull;    // rem==0 -> 0
            const u64 pvv = pv & valid;
            cuP[r] = cuF + __popcll(pvv);
            const u64 A1 = L[wb + tk[4 + r]] & pvv;
            const u64 A2 = A1 & L[2048 + wb + tk[3 + r]];
            const u64 A3 = A2 & L[4096 + wb + tk[2 + r]];
            const u64 A4 = A3 & L[6144 + wb + tk[1 + r]];
            hh[r][0] += __popcll(A1);
            hh[r][1] += __popcll(A2);
            hh[r][2] += __popcll(A3);
            hh[r][3] += __popcll(A4);
        }
    }

    // Epilogue: c_i = wave-sum of h_i (packed 2x16-bit), then write 648 chans.
    #pragma unroll
    for (int r = 0; r < 8; ++r) {
        const int q = q0 + r;
        int p01 = hh[r][0] | (hh[r][1] << 16);
        int p23 = hh[r][2] | (hh[r][3] << 16);
        #pragma unroll
        for (int sft = 1; sft < 64; sft <<= 1) {
            p01 += __shfl_xor(p01, sft);
            p23 += __shfl_xor(p23, sft);
        }
        const int c1 = p01 & 0xffff, c2 = p01 >> 16;
        const int c3 = p23 & 0xffff, c4 = p23 >> 16;

        float* op = out + ((size_t)q * BATCH + b) * DMODEL;
        #pragma unroll
        for (int m = 0; m <= 4; ++m) {   // one-hot blocks, sentinel -> zeros
            const bool sent = (q0 + r - m) < 0;
            op[m * 64 + lane] = (!sent && lane == tk[4 + r - m]) ? 1.f : 0.f;
        }
        op[320 + lane] = (float)hh[r][0] / (float)(c1 ? c1 : 1);
        op[384 + lane] = (float)hh[r][1] / (float)(c2 ? c2 : 1);
        op[448 + lane] = (float)hh[r][2] / (float)(c3 ? c3 : 1);
        op[512 + lane] = (float)hh[r][3] / (float)(c4 ? c4 : 1);
        op[576 + lane] = (float)cuP[r] / (float)(q ? q : 1);
        if (lane < 8) {
            float v = 0.f;
            if (lane == 0) v = (float)c1;
            else if (lane == 1) v = (float)c2;
            else if (lane == 2) v = (float)c3;
            else if (lane == 3) v = (float)c4;
            else if (lane == 4) v = (float)q;
            op[640 + lane] = v;
        }
    }
}

extern "C" void kernel_launch(void* const* d_in, const int* in_sizes, int n_in,
                              void* d_out, int out_size, void* d_ws, size_t ws_size,
                              hipStream_t stream) {
    const int* src = (const int*)d_in[0];
    float* out = (float*)d_out;
    u64* P  = (u64*)d_ws;          // 16384 u64
    u64* SH = P + 16384;           // 65536 u64 (4 tables x 8 batch)
    int* sT = (int*)(P + 81920);   // 16384 int

    build_kernel<<<dim3(NBLK, BATCH), 64, 0, stream>>>(src, P, SH, sT);
    // 256 octets per b / 4 waves per WG -> grid (64, 8)
    compute_kernel<<<dim3(64, BATCH), 256, 0, stream>>>(P, SH, sT, out);
}

// Round 5
// 84.502 us; speedup vs baseline: 1.1357x; 1.1357x over previous
//
#include <hip/hip_runtime.h>

typedef unsigned long long u64;

#define S_LEN 2048
#define BATCH 8
#define DMODEL 648

// Single fused kernel. Grid (64, 8) x 256 threads, 2 WG/CU (64 KiB LDS).
//
// LDS tables (per batch column b, built per-WG):
//   LP[w*64+t]          bit jj: src[64w+jj]   == t   (P)
//   C1[2*(w*64+t)+0]    bit jj: src[64w+jj-1] == t   (S1)
//   C1[2*(w*64+t)+1]    bit jj: src[64w+jj-2] == t   (S2)
//   LS3[w*64+t]         bit jj: src[64w+jj-3] == t   (S3)
// Depth-4 row = (S3[w] << 1) | (S3[w-1] >> 63).
//
// Each wave (o = bx*4+wv in 0..255 per b) handles quartets o and 511-o
// (4 q's each) -> every wave does ~32 block-iterations (balanced).
// Lane = token id t:
//   h_i[t] += popc(A_i),  A1 = S1row & P[w][t], A_i = A_{i-1} & row_i
//   c_i = wave-sum h_i (packed shfl reduce), cu[t] += popc(P[w][t]).
__global__ __launch_bounds__(256, 2) void fused_kernel(const int* __restrict__ src,
                                                       float* __restrict__ out) {
    __shared__ __align__(16) u64 C1[2 * 2048];  // 32 KiB {S1,S2} interleaved
    __shared__ u64 LP[2048];                    // 16 KiB
    __shared__ u64 LS3[2048];                   // 16 KiB

    const int b = blockIdx.y;
    const int tid = threadIdx.x;
    const int lane = tid & 63;
    const int wv = tid >> 6;

    // ---- build tables in LDS ----
    int myt[8];
    #pragma unroll
    for (int k = 0; k < 8; ++k) {               // stage tokens into regs
        const int i = tid + 256 * k;
        myt[k] = src[i * BATCH + b];
        LP[i] = 0;
    }
    __syncthreads();
    #pragma unroll
    for (int k = 0; k < 8; ++k) {
        const int i = tid + 256 * k;
        atomicOr(&LP[(i & ~63) | myt[k]], 1ull << (i & 63));
    }
    __syncthreads();
    #pragma unroll
    for (int k = 0; k < 8; ++k) {
        const int i = tid + 256 * k;
        const u64 m = LP[i];
        const u64 mp = (i >= 64) ? LP[i - 64] : 0ull;
        C1[2 * i]     = (m << 1) | (mp >> 63);
        C1[2 * i + 1] = (m << 2) | (mp >> 62);
        LS3[i]        = (m << 3) | (mp >> 61);
    }
    __syncthreads();

    const int o = blockIdx.x * 4 + wv;          // 0..255 per b

    #pragma unroll 1
    for (int half = 0; half < 2; ++half) {
        const int quart = half ? (511 - o) : o;
        const int q0 = quart << 2;

        int tk[8];
        #pragma unroll
        for (int i = 0; i < 8; ++i) {
            const int idx = q0 - 4 + i;
            tk[i] = (idx >= 0) ? src[idx * BATCH + b] : 0;  // clamp: dead rows
        }

        int h1[4] = {}, h2[4] = {}, h3[4] = {}, h4[4] = {};
        int cuP[4];
        int cuF = 0;
        const int wq = q0 >> 6, rem0 = q0 & 63;

        for (int w = 0; w < wq; ++w) {
            const int wb = w << 6;
            const int pb = w ? (wb - 64) : 0;   // prev-block base (clamped)
            const u64 pv = LP[wb + lane];
            cuF += __popcll(pv);
            // heads: pair at tk[3] (S2 for r=0), pair at tk[1] (depth4 r=0)
            ulonglong2 pc = *(const ulonglong2*)&C1[2 * (wb + tk[3])];
            u64 p3c = LS3[wb + tk[1]];
            u64 p3p = w ? LS3[pb + tk[1]] : 0ull;
            #pragma unroll
            for (int r = 0; r < 4; ++r) {
                const ulonglong2 c = *(const ulonglong2*)&C1[2 * (wb + tk[4 + r])];
                const u64 s3c = LS3[wb + tk[2 + r]];
                const u64 s3p = w ? LS3[pb + tk[2 + r]] : 0ull;
                const u64 A1 = c.x & pv;          // S1[tk[4+r]]
                const u64 A2 = A1 & pc.y;         // S2[tk[3+r]] (prev pair)
                const u64 A3 = A2 & s3c;          // S3[tk[2+r]]
                const u64 A4 = A3 & ((p3c << 1) | (p3p >> 63));  // S4[tk[1+r]]
                h1[r] += __popcll(A1);
                h2[r] += __popcll(A2);
                h3[r] += __popcll(A3);
                h4[r] += __popcll(A4);
                pc = c; p3c = s3c; p3p = s3p;
            }
        }

        {   // partial block w = wq: j-bits jj < rem0 + r
            const int wb = wq << 6;
            const int pb = wq ? (wb - 64) : 0;
            const u64 pv = LP[wb + lane];
            ulonglong2 pc = *(const ulonglong2*)&C1[2 * (wb + tk[3])];
            u64 p3c = LS3[wb + tk[1]];
            u64 p3p = wq ? LS3[pb + tk[1]] : 0ull;
            #pragma unroll
            for (int r = 0; r < 4; ++r) {
                const int rem = rem0 + r;                  // <= 63
                const u64 valid = (1ull << rem) - 1ull;    // rem==0 -> 0
                const u64 pvv = pv & valid;
                cuP[r] = cuF + __popcll(pvv);
                const ulonglong2 c = *(const ulonglong2*)&C1[2 * (wb + tk[4 + r])];
                const u64 s3c = LS3[wb + tk[2 + r]];
                const u64 s3p = wq ? LS3[pb + tk[2 + r]] : 0ull;
                const u64 A1 = c.x & pvv;
                const u64 A2 = A1 & pc.y;
                const u64 A3 = A2 & s3c;
                const u64 A4 = A3 & ((p3c << 1) | (p3p >> 63));
                h1[r] += __popcll(A1);
                h2[r] += __popcll(A2);
                h3[r] += __popcll(A3);
                h4[r] += __popcll(A4);
                pc = c; p3c = s3c; p3p = s3p;
            }
        }

        // c_i = wave-sum of h_i; 4 independent packed reduce chains (ILP)
        int c1v[4], c2v[4], c3v[4], c4v[4];
        #pragma unroll
        for (int r = 0; r < 4; ++r) {
            int p01 = h1[r] | (h2[r] << 16);
            int p23 = h3[r] | (h4[r] << 16);
            #pragma unroll
            for (int sft = 1; sft < 64; sft <<= 1) {
                p01 += __shfl_xor(p01, sft);
                p23 += __shfl_xor(p23, sft);
            }
            c1v[r] = p01 & 0xffff; c2v[r] = p01 >> 16;
            c3v[r] = p23 & 0xffff; c4v[r] = p23 >> 16;
        }

        #pragma unroll
        for (int r = 0; r < 4; ++r) {
            const int q = q0 + r;
            float* op = out + ((size_t)q * BATCH + b) * DMODEL;
            #pragma unroll
            for (int m = 0; m <= 4; ++m) {   // one-hot blocks, sentinel -> 0
                const bool sent = (q - m) < 0;
                op[m * 64 + lane] = (!sent && lane == tk[4 + r - m]) ? 1.f : 0.f;
            }
            op[320 + lane] = (float)h1[r] / (float)(c1v[r] ? c1v[r] : 1);
            op[384 + lane] = (float)h2[r] / (float)(c2v[r] ? c2v[r] : 1);
            op[448 + lane] = (float)h3[r] / (float)(c3v[r] ? c3v[r] : 1);
            op[512 + lane] = (float)h4[r] / (float)(c4v[r] ? c4v[r] : 1);
            op[576 + lane] = (float)cuP[r] / (float)(q ? q : 1);
            if (lane < 8) {
                float v = 0.f;
                if (lane == 0) v = (float)c1v[r];
                else if (lane == 1) v = (float)c2v[r];
                else if (lane == 2) v = (float)c3v[r];
                else if (lane == 3) v = (float)c4v[r];
                else if (lane == 4) v = (float)q;
                op[640 + lane] = v;
            }
        }
    }
}

extern "C" void kernel_launch(void* const* d_in, const int* in_sizes, int n_in,
                              void* d_out, int out_size, void* d_ws, size_t ws_size,
                              hipStream_t stream) {
    const int* src = (const int*)d_in[0];
    float* out = (float*)d_out;
    fused_kernel<<<dim3(64, BATCH), 256, 0, stream>>>(src, out);
}